// Round 4
// baseline (450.504 us; speedup 1.0000x reference)
//
#include <hip/hip_runtime.h>
#include <math.h>

// E=8, TOP=2, C=128, H=96, W=96, B=8, NUM_GATES=4, KH=3
#define CHW 9216
#define OPG 9437184  // 8*128*96*96

typedef unsigned short u16;
typedef __attribute__((ext_vector_type(8))) short short8;   // 8 x bf16 (4 VGPR)
typedef __attribute__((ext_vector_type(4))) float f32x4;

// ws layout (bytes):
// [0, 8192)            gating (floats): x_gap[1024]; idx2[4][8][2] int @1344f; wt2[4][8][2] @1408f
// [8192, 18882560)     X_t  bf16 [b][hf][h][w][c64]  (c swizzled: c^((w&7)<<3))
// [18882560, 21241856) A_t2 bf16 [e][hf][r][ck][mi][mb][lane][8]  (wave-fragment order)
// [21241856, 21504000) Wp_t bf16 [e][o][c128]
#define WS_XT  8192
#define WS_AT  18882560
#define WS_WPT 21241856

__device__ __forceinline__ u16 f2bf(float f) {
    unsigned u = __float_as_uint(f);
    u += 0x7fff + ((u >> 16) & 1);      // RNE
    return (u16)(u >> 16);
}

// async global->LDS, 16B per lane; LDS dest must be wave-uniform base + lane*16
__device__ __forceinline__ void gload_lds16(const void* g, void* l) {
    __builtin_amdgcn_global_load_lds(
        (const __attribute__((address_space(1))) void*)g,
        (__attribute__((address_space(3))) void*)l, 16, 0, 0);
}

// ---------------------------------------------------------------- x_gap
__global__ void gap_kernel(const float* __restrict__ x, float* __restrict__ xgap) {
    int bc = blockIdx.x;
    const float* p = x + (size_t)bc * CHW;
    float s = 0.f;
    for (int i = threadIdx.x; i < CHW; i += 256) s += p[i];
    __shared__ float red[256];
    red[threadIdx.x] = s;
    __syncthreads();
    for (int off = 128; off > 0; off >>= 1) {
        if (threadIdx.x < off) red[threadIdx.x] += red[threadIdx.x + off];
        __syncthreads();
    }
    if (threadIdx.x == 0) xgap[bc] = red[0] * (1.0f / 9216.0f);
}

// ---------------------------------------------------------------- gating (exact fp32)
__global__ void gate_kernel(const float* __restrict__ G, float* __restrict__ ws,
                            float* __restrict__ loss_out) {
    __shared__ float gap_s[1024];
    __shared__ float logits[64];
    __shared__ float probs[64];
    __shared__ float vsum[8];
    __shared__ float losses[4];
    int t = threadIdx.x;
    for (int i = t; i < 1024; i += 64) gap_s[i] = ws[i];
    int b = t >> 3, e = t & 7;
    int* iw = (int*)(ws + 1344);
    float* wt = ws + 1408;
    __syncthreads();
    for (int g = 0; g < 4; ++g) {
        float acc = 0.f;
        const float* Gg = G + g * 1024;
        for (int c = 0; c < 128; ++c) acc += gap_s[b * 128 + c] * Gg[c * 8 + e];
        logits[t] = acc;
        __syncthreads();
        float m = -1e30f;
        for (int j = 0; j < 8; ++j) m = fmaxf(m, logits[b * 8 + j]);
        float den = 0.f;
        for (int j = 0; j < 8; ++j) den += expf(logits[b * 8 + j] - m);
        float pr = expf(acc - m) / den;
        probs[t] = pr;
        __syncthreads();
        if (e == 0) {
            int i0 = 0; float v0 = probs[b * 8];
            for (int j = 1; j < 8; ++j) { float v = probs[b * 8 + j]; if (v > v0) { v0 = v; i0 = j; } }
            int i1 = -1; float v1 = -1e30f;
            for (int j = 0; j < 8; ++j) { if (j == i0) continue; float v = probs[b * 8 + j]; if (v > v1) { v1 = v; i1 = j; } }
            float r = expf(v1 - v0);              // softmax over [v0,v1]
            float inv = 1.f / (1.f + r);
            iw[g * 16 + b * 2 + 0] = i0;
            iw[g * 16 + b * 2 + 1] = i1;
            wt[g * 16 + b * 2 + 0] = inv;
            wt[g * 16 + b * 2 + 1] = r * inv;
        }
        if (t < 8) {
            float v = 0.f;
            for (int bb = 0; bb < 8; ++bb) v += probs[bb * 8 + t];
            vsum[t] = v;
        }
        __syncthreads();
        if (t == 0) {
            float mean = 0.f;
            for (int j = 0; j < 8; ++j) mean += vsum[j];
            mean *= 0.125f;
            float var = 0.f;
            for (int j = 0; j < 8; ++j) { float d = vsum[j] - mean; var += d * d; }
            var *= (1.f / 7.f);
            losses[g] = var / (mean * mean + 1e-10f);
        }
        __syncthreads();
    }
    if (t == 0) loss_out[0] = 0.25f * (losses[0] + losses[1] + losses[2] + losses[3]);
}

// ---------------------------------------------------------------- pre: x -> bf16 swizzled
__global__ void pre_x(const float* __restrict__ x, u16* __restrict__ Xt) {
    int h = blockIdx.x, b = blockIdx.y, t = threadIdx.x;
    __shared__ u16 lds[12288];
    const float* xb = x + ((size_t)b * 128) * CHW + h * 96;
    for (int i = t; i < 12288; i += 256) {
        int c = i / 96, w = i - c * 96;
        lds[(c >> 6) * 6144 + w * 64 + ((c & 63) ^ ((w & 7) << 3))] = f2bf(xb[(size_t)c * CHW + w]);
    }
    __syncthreads();
    const unsigned* l32 = (const unsigned*)lds;
    unsigned* o32 = (unsigned*)Xt;
    for (int i = t; i < 6144; i += 256) {
        int hf = (i >= 3072) ? 1 : 0;
        int rem = i - hf * 3072;
        o32[((size_t)(b * 2 + hf) * 96 + h) * 3072 + rem] = l32[i];
    }
}

// ---------------------------------------------------------------- pre: Wc -> A_t2 (fragment order)
// At2 u16 index: (((((e*2+hf)*9+r)*2+ck)*2+mi)*4+mb)*512 + lane*8 + s
// value = Wc[e][o=mi*64+mb*16+(lane&15)][cin=hf*64+ck*32+(lane>>4)*8+s][tap r]
__global__ void pre_wc2(const float* __restrict__ Wc, u16* __restrict__ At2) {
    int idx = blockIdx.x * 256 + threadIdx.x;          // < 1179648
    int s = idx & 7;
    int lane = (idx >> 3) & 63;
    int mb = (idx >> 9) & 3;
    int mi = (idx >> 11) & 1;
    int ck = (idx >> 12) & 1;
    int rem = idx >> 13;                                // 0..143
    int r = rem % 9;
    int rem2 = rem / 9;                                 // 0..15
    int hf = rem2 & 1;
    int e = rem2 >> 1;
    int l15 = lane & 15, quad = lane >> 4;
    int o = mi * 64 + mb * 16 + l15;
    int cin = hf * 64 + ck * 32 + quad * 8 + s;
    size_t src = (((size_t)e * 128 + o) * 128 + cin) * 9 + r;
    At2[idx] = f2bf(Wc[src]);
}

// ---------------------------------------------------------------- pre: Wp -> bf16
__global__ void pre_wp(const float* __restrict__ Wp, u16* __restrict__ Wpt) {
    int i = blockIdx.x * 256 + threadIdx.x;
    if (i < 131072) Wpt[i] = f2bf(Wp[i]);
}

// ---------------------------------------------------------------- fused dual-expert gate block
// Block: (hs, b, g) -> 2 output rows, both top-2 experts, writes out[g] once (no atomics).
// 512 threads = 8 waves: mi = M-half (64 ch), ni = quarter of 192 px (48 px, j=3 tiles).
// Conv: 36 phases. Per phase (T3/T4 lgkm-counted discipline):
//   STAGE(u+2) -> LDS ring slot (u+2)%3        [2 vmem]
//   bv(u) ds_read (3)                           [consumed this phase]
//   afr(u+1) ds_read (8) into 2-slot REG ring   [consumed NEXT phase -> in flight across
//                                                the barrier; barrier pins them (ds ops
//                                                can't cross s_barrier); in-order lgkm
//                                                completion => covered by bv(u+1) wait]
//   setprio(1) MFMA x24 on afr(u) setprio(0)
//   s_waitcnt vmcnt(0)  [free: stage issued ~900cy earlier, L2-resident]
//   s_barrier
__launch_bounds__(512, 2)
__global__ void expert_kernel(const u16* __restrict__ Xt, const u16* __restrict__ At2,
                              const u16* __restrict__ Wpt,
                              const float* __restrict__ bc, const float* __restrict__ bp,
                              const float* __restrict__ ws, float* __restrict__ out) {
    int hs = blockIdx.x, b = blockIdx.y, g = blockIdx.z;
    int h0 = hs * 2;
    int t = threadIdx.x, lane = t & 63, wv = t >> 6;
    int mi = wv & 1, ni = wv >> 1;                 // ni 0..3
    int l15 = lane & 15, quad = lane >> 4, q8 = quad * 8;
    int nrow = ni >> 1;                            // local output row 0/1
    int ncb = (ni & 1) * 48;                       // pixel-col base

    const int* iw = (const int*)(ws + 1344);
    const float* wt = ws + 1408;
    int ee[2];
    float wwt[2];
    ee[0] = iw[g * 16 + b * 2 + 0]; ee[1] = iw[g * 16 + b * 2 + 1];
    wwt[0] = wt[g * 16 + b * 2 + 0]; wwt[1] = wt[g * 16 + b * 2 + 1];

    // LDS: halo Hs[4][98][64] bf16 @0 (50176 B) | A-ring @50176: 3 x 16384 B = 99328 total
    //      epilogue overlays @0: part_s[192][12] f32 (9216) + v_s[192][128] bf16 (49152)
    __shared__ __align__(16) char smem[99328];
    u16* Hs = (u16*)smem;                          // halo row stride 6272 u16 = 12544 B
    float* part_s = (float*)smem;
    u16* v_s = (u16*)(smem + 9216);

    f32x4 zero = {0.f, 0.f, 0.f, 0.f};
    f32x4 acc[2][12];                              // [expert][mb*3 + j]
    #pragma unroll
    for (int i = 0; i < 12; ++i) { acc[0][i] = zero; acc[1][i] = zero; }

    int abase = mi * 2048 + lane * 8;              // u16 offset within a ring slot (per expert)

    const u16* Ab0 = At2 + (size_t)(ee[0] * 2) * 73728;   // expert bases (hf=0)
    const u16* Ab1 = At2 + (size_t)(ee[1] * 2) * 73728;

    #define ASRC(P, U) ((P) + ((U) >= 18 ? 73728 + ((U) - 18) * 4096 : (U) * 4096))
    #define STAGE(U) { u16* ab_ = (u16*)(smem + 50176 + ((U) % 3) * 16384);          \
                       gload_lds16(ASRC(Ab0, (U)) + t * 8, ab_ + t * 8);             \
                       gload_lds16(ASRC(Ab1, (U)) + t * 8, ab_ + 4096 + t * 8); }

    // ======== prologue: zero borders/OOB rows, stage hf0 halo, stage u=0,1 ========
    {
        uint4 z; z.x = z.y = z.z = z.w = 0u;
        #pragma unroll
        for (int rr = 0; rr < 4; ++rr) {
            int row = h0 - 1 + rr;
            if (row < 0 || row >= 96)              // OOB rows: zero once, valid for both hf
                for (int i = t; i < 784; i += 512) *(uint4*)(Hs + rr * 6272 + i * 8) = z;
        }
        if (t < 64) {                              // border cols 0 / 97 (persist across hf)
            int rr = t >> 4, cs = (t >> 3) & 1, p = t & 7;
            *(uint4*)(Hs + rr * 6272 + cs * 97 * 64 + p * 8) = z;
        }
        const u16* Xb = Xt + (size_t)(b * 2 + 0) * 96 * 6144;
        #pragma unroll
        for (int rr = 0; rr < 4; ++rr) {
            int row = h0 - 1 + rr;
            if (row >= 0 && row < 96) {
                const u16* src = Xb + (size_t)row * 6144;
                u16* dst = Hs + rr * 6272 + 64;
                for (int i = t; i < 768; i += 512) gload_lds16(src + i * 8, dst + i * 8);
            }
        }
    }
    STAGE(0); STAGE(1);
    __syncthreads();                               // full drain once

    // preload afr slot for step 0 (ring slot 0)
    short8 afr[2][2][4];                           // [parity][expert][mb]
    {
        const u16* ab = (const u16*)(smem + 50176);
        #pragma unroll
        for (int mb = 0; mb < 4; ++mb) {
            afr[0][0][mb] = *(const short8*)(ab + abase + mb * 512);
            afr[0][1][mb] = *(const short8*)(ab + 4096 + abase + mb * 512);
        }
    }

    // ======== conv: 36 phases ========
    #pragma unroll
    for (int u = 0; u < 36; ++u) {
        if (u == 18) {
            // hf boundary: restage halo (hf0 bv reads all completed before the phase-17
            // barrier; this DMA is issued after it). One-time exposed wait ~400cy.
            const u16* Xb = Xt + (size_t)(b * 2 + 1) * 96 * 6144;
            #pragma unroll
            for (int rr = 0; rr < 4; ++rr) {
                int row = h0 - 1 + rr;
                if (row >= 0 && row < 96) {
                    const u16* src = Xb + (size_t)row * 6144;
                    u16* dst = Hs + rr * 6272 + 64;
                    for (int i = t; i < 768; i += 512) gload_lds16(src + i * 8, dst + i * 8);
                }
            }
            asm volatile("s_waitcnt vmcnt(0)" ::: "memory");
            __builtin_amdgcn_s_barrier();
        }
        if (u < 34) STAGE(u + 2);

        int s = (u >= 18) ? u - 18 : u;            // compile-time after unroll
        int r = s >> 1, ck = s & 1;
        int dyi = r / 3, dxi = r - dyi * 3;
        int hb = (nrow + dyi) * 12544;

        short8 bv[3];                              // current-step B-frags (read at top)
        #pragma unroll
        for (int j = 0; j < 3; ++j) {
            int col = ncb + j * 16 + l15 + dxi;
            int ba = hb + col * 128 + ((q8 ^ (((col - 1) & 7) << 3)) << 1);
            bv[j] = *(const short8*)(smem + (ba ^ (ck << 6)));
        }
        if (u < 35) {                              // prefetch next step's A-frags into reg ring
            const u16* ab = (const u16*)(smem + 50176 + ((u + 1) % 3) * 16384);
            #pragma unroll
            for (int mb = 0; mb < 4; ++mb) {
                afr[(u + 1) & 1][0][mb] = *(const short8*)(ab + abase + mb * 512);
                afr[(u + 1) & 1][1][mb] = *(const short8*)(ab + 4096 + abase + mb * 512);
            }
        }
        __builtin_amdgcn_s_setprio(1);
        #pragma unroll
        for (int mb = 0; mb < 4; ++mb)
            #pragma unroll
            for (int j = 0; j < 3; ++j) {
                acc[0][mb * 3 + j] = __builtin_amdgcn_mfma_f32_16x16x32_bf16(afr[u & 1][0][mb], bv[j], acc[0][mb * 3 + j], 0, 0, 0);
                acc[1][mb * 3 + j] = __builtin_amdgcn_mfma_f32_16x16x32_bf16(afr[u & 1][1][mb], bv[j], acc[1][mb * 3 + j], 0, 0, 0);
            }
        __builtin_amdgcn_s_setprio(0);
        asm volatile("s_waitcnt vmcnt(0)" ::: "memory");
        __builtin_amdgcn_s_barrier();
    }
    #undef STAGE
    #undef ASRC

    // ======== epilogue per expert: bias+relu+squash -> v_s -> pointwise ========
    #pragma unroll
    for (int xp = 0; xp < 2; ++xp) {
        int e_ = ee[xp];
        __syncthreads();   // xp=0: conv LDS reads done; xp=1: pw0's v_s reads done
        #pragma unroll
        for (int j = 0; j < 3; ++j) {
            int n = ni * 48 + j * 16 + l15;
            float ssum = 0.f;
            #pragma unroll
            for (int mb = 0; mb < 4; ++mb) {
                f32x4 a = acc[xp][mb * 3 + j];
                #pragma unroll
                for (int rg = 0; rg < 4; ++rg) {
                    float u = fmaxf(a[rg] + bc[e_ * 128 + mi * 64 + mb * 16 + quad * 4 + rg], 0.f);
                    a[rg] = u; ssum += u * u;
                }
                acc[xp][mb * 3 + j] = a;
            }
            part_s[n * 12 + mi * 4 + quad] = ssum;
        }
        __syncthreads();
        #pragma unroll
        for (int j = 0; j < 3; ++j) {
            int n = ni * 48 + j * 16 + l15;
            f32x4 p0 = *(const f32x4*)(part_s + n * 12);
            f32x4 p1 = *(const f32x4*)(part_s + n * 12 + 4);
            float sn2 = p0[0] + p0[1] + p0[2] + p0[3] + p1[0] + p1[1] + p1[2] + p1[3];
            float fsj = sn2 / ((1.f + sn2) * sqrtf(sn2 + 1e-8f));
            int sw = (n & 7) << 3;
            #pragma unroll
            for (int mb = 0; mb < 4; ++mb) {
                f32x4 a = acc[xp][mb * 3 + j];
                short4 pk;
                pk.x = (short)f2bf(a[0] * fsj); pk.y = (short)f2bf(a[1] * fsj);
                pk.z = (short)f2bf(a[2] * fsj); pk.w = (short)f2bf(a[3] * fsj);
                int cb = mb * 16 + quad * 4;
                *(short4*)(v_s + n * 128 + ((cb ^ sw) | (mi << 6))) = pk;
            }
        }
        __syncthreads();
        #pragma unroll
        for (int i = 0; i < 12; ++i) acc[xp][i] = zero;
        const u16* We_ = Wpt + (size_t)e_ * 16384;
        #pragma unroll
        for (int kk = 0; kk < 4; ++kk) {
            short8 af[4];
            #pragma unroll
            for (int mb = 0; mb < 4; ++mb)
                af[mb] = *(const short8*)(We_ + (mi * 64 + mb * 16 + l15) * 128 + kk * 32 + q8);
            short8 bvv[3];
            #pragma unroll
            for (int j = 0; j < 3; ++j) {
                int n = ni * 48 + j * 16 + l15;
                int sw = (n & 7) << 3;
                int pos = ((kk & 2) << 5) | ((((kk & 1) << 5) + q8) ^ sw);
                bvv[j] = *(const short8*)(v_s + n * 128 + pos);
            }
            #pragma unroll
            for (int mb = 0; mb < 4; ++mb)
                #pragma unroll
                for (int j = 0; j < 3; ++j)
                    acc[xp][mb * 3 + j] = __builtin_amdgcn_mfma_f32_16x16x32_bf16(af[mb], bvv[j], acc[xp][mb * 3 + j], 0, 0, 0);
        }
    }

    // ======== mix + store (exactly once, coalesced) ========
    int row = h0 + nrow;
    #pragma unroll
    for (int mb = 0; mb < 4; ++mb)
        #pragma unroll
        for (int rg = 0; rg < 4; ++rg) {
            int o = mi * 64 + mb * 16 + quad * 4 + rg;
            float y0b = bp[ee[0] * 128 + o];
            float y1b = bp[ee[1] * 128 + o];
            size_t obase = (size_t)g * OPG + ((size_t)(b * 128 + o)) * CHW + (size_t)row * 96;
            #pragma unroll
            for (int j = 0; j < 3; ++j) {
                float y0 = acc[0][mb * 3 + j][rg] + y0b;
                float y1 = acc[1][mb * 3 + j][rg] + y1b;
                out[obase + ncb + j * 16 + l15] = wwt[0] * y0 + wwt[1] * y1;
            }
        }
}

// ---------------------------------------------------------------- launch
extern "C" void kernel_launch(void* const* d_in, const int* in_sizes, int n_in,
                              void* d_out, int out_size, void* d_ws, size_t ws_size,
                              hipStream_t stream) {
    const float* x  = (const float*)d_in[0];
    const float* G  = (const float*)d_in[1];
    const float* Wc = (const float*)d_in[2];
    const float* bc = (const float*)d_in[3];
    const float* Wp = (const float*)d_in[4];
    const float* bp = (const float*)d_in[5];
    float* out = (float*)d_out;
    float* ws  = (float*)d_ws;
    u16* Xt  = (u16*)((char*)d_ws + WS_XT);
    u16* At2 = (u16*)((char*)d_ws + WS_AT);
    u16* Wpt = (u16*)((char*)d_ws + WS_WPT);

    gap_kernel<<<dim3(1024), dim3(256), 0, stream>>>(x, ws);
    gate_kernel<<<dim3(1), dim3(64), 0, stream>>>(G, ws, out + (size_t)4 * OPG);
    pre_x<<<dim3(96, 8), dim3(256), 0, stream>>>(x, Xt);
    pre_wc2<<<dim3(4608), dim3(256), 0, stream>>>(Wc, At2);
    pre_wp<<<dim3(512), dim3(256), 0, stream>>>(Wp, Wpt);
    expert_kernel<<<dim3(48, 8, 4), dim3(512), 0, stream>>>(Xt, At2, Wpt, bc, bp, ws, out);
}

// Round 5
// 430.197 us; speedup vs baseline: 1.0472x; 1.0472x over previous
//
#include <hip/hip_runtime.h>
#include <math.h>

// E=8, TOP=2, C=128, H=96, W=96, B=8, NUM_GATES=4, KH=3
#define CHW 9216
#define OPG 9437184  // 8*128*96*96

typedef unsigned short u16;
typedef __attribute__((ext_vector_type(8))) short short8;   // 8 x bf16 (4 VGPR)
typedef __attribute__((ext_vector_type(4))) float f32x4;

// ws layout (bytes):
// [0, 8192)            gating (floats): x_gap[1024]; idx2[4][8][2] int @1344f; wt2[4][8][2] @1408f
// [8192, 18882560)     X_t  bf16 [b][hf][h][w][c64]  (c swizzled: c^((w&7)<<3))
// [18882560, 21241856) A_t2 bf16 [e][hf][r][ck][mi][mb][lane][8]  (wave-fragment order)
// [21241856, 21504000) Wp_t bf16 [e][o][c128]
#define WS_XT  8192
#define WS_AT  18882560
#define WS_WPT 21241856

__device__ __forceinline__ u16 f2bf(float f) {
    unsigned u = __float_as_uint(f);
    u += 0x7fff + ((u >> 16) & 1);      // RNE
    return (u16)(u >> 16);
}

// async global->LDS, 16B per lane; LDS dest must be wave-uniform base + lane*16
__device__ __forceinline__ void gload_lds16(const void* g, void* l) {
    __builtin_amdgcn_global_load_lds(
        (const __attribute__((address_space(1))) void*)g,
        (__attribute__((address_space(3))) void*)l, 16, 0, 0);
}

// ---------------------------------------------------------------- x_gap
__global__ void gap_kernel(const float* __restrict__ x, float* __restrict__ xgap) {
    int bc = blockIdx.x;
    const float* p = x + (size_t)bc * CHW;
    float s = 0.f;
    for (int i = threadIdx.x; i < CHW; i += 256) s += p[i];
    __shared__ float red[256];
    red[threadIdx.x] = s;
    __syncthreads();
    for (int off = 128; off > 0; off >>= 1) {
        if (threadIdx.x < off) red[threadIdx.x] += red[threadIdx.x + off];
        __syncthreads();
    }
    if (threadIdx.x == 0) xgap[bc] = red[0] * (1.0f / 9216.0f);
}

// ---------------------------------------------------------------- gating (exact fp32)
__global__ void gate_kernel(const float* __restrict__ G, float* __restrict__ ws,
                            float* __restrict__ loss_out) {
    __shared__ float gap_s[1024];
    __shared__ float logits[64];
    __shared__ float probs[64];
    __shared__ float vsum[8];
    __shared__ float losses[4];
    int t = threadIdx.x;
    for (int i = t; i < 1024; i += 64) gap_s[i] = ws[i];
    int b = t >> 3, e = t & 7;
    int* iw = (int*)(ws + 1344);
    float* wt = ws + 1408;
    __syncthreads();
    for (int g = 0; g < 4; ++g) {
        float acc = 0.f;
        const float* Gg = G + g * 1024;
        for (int c = 0; c < 128; ++c) acc += gap_s[b * 128 + c] * Gg[c * 8 + e];
        logits[t] = acc;
        __syncthreads();
        float m = -1e30f;
        for (int j = 0; j < 8; ++j) m = fmaxf(m, logits[b * 8 + j]);
        float den = 0.f;
        for (int j = 0; j < 8; ++j) den += expf(logits[b * 8 + j] - m);
        float pr = expf(acc - m) / den;
        probs[t] = pr;
        __syncthreads();
        if (e == 0) {
            int i0 = 0; float v0 = probs[b * 8];
            for (int j = 1; j < 8; ++j) { float v = probs[b * 8 + j]; if (v > v0) { v0 = v; i0 = j; } }
            int i1 = -1; float v1 = -1e30f;
            for (int j = 0; j < 8; ++j) { if (j == i0) continue; float v = probs[b * 8 + j]; if (v > v1) { v1 = v; i1 = j; } }
            float r = expf(v1 - v0);              // softmax over [v0,v1]
            float inv = 1.f / (1.f + r);
            iw[g * 16 + b * 2 + 0] = i0;
            iw[g * 16 + b * 2 + 1] = i1;
            wt[g * 16 + b * 2 + 0] = inv;
            wt[g * 16 + b * 2 + 1] = r * inv;
        }
        if (t < 8) {
            float v = 0.f;
            for (int bb = 0; bb < 8; ++bb) v += probs[bb * 8 + t];
            vsum[t] = v;
        }
        __syncthreads();
        if (t == 0) {
            float mean = 0.f;
            for (int j = 0; j < 8; ++j) mean += vsum[j];
            mean *= 0.125f;
            float var = 0.f;
            for (int j = 0; j < 8; ++j) { float d = vsum[j] - mean; var += d * d; }
            var *= (1.f / 7.f);
            losses[g] = var / (mean * mean + 1e-10f);
        }
        __syncthreads();
    }
    if (t == 0) loss_out[0] = 0.25f * (losses[0] + losses[1] + losses[2] + losses[3]);
}

// ---------------------------------------------------------------- pre: x -> bf16 swizzled
__global__ void pre_x(const float* __restrict__ x, u16* __restrict__ Xt) {
    int h = blockIdx.x, b = blockIdx.y, t = threadIdx.x;
    __shared__ u16 lds[12288];
    const float* xb = x + ((size_t)b * 128) * CHW + h * 96;
    for (int i = t; i < 12288; i += 256) {
        int c = i / 96, w = i - c * 96;
        lds[(c >> 6) * 6144 + w * 64 + ((c & 63) ^ ((w & 7) << 3))] = f2bf(xb[(size_t)c * CHW + w]);
    }
    __syncthreads();
    const unsigned* l32 = (const unsigned*)lds;
    unsigned* o32 = (unsigned*)Xt;
    for (int i = t; i < 6144; i += 256) {
        int hf = (i >= 3072) ? 1 : 0;
        int rem = i - hf * 3072;
        o32[((size_t)(b * 2 + hf) * 96 + h) * 3072 + rem] = l32[i];
    }
}

// ---------------------------------------------------------------- pre: Wc -> A_t2 (fragment order)
// At2 u16 index: (((((e*2+hf)*9+r)*2+ck)*2+mi)*4+mb)*512 + lane*8 + s
// value = Wc[e][o=mi*64+mb*16+(lane&15)][cin=hf*64+ck*32+(lane>>4)*8+s][tap r]
__global__ void pre_wc2(const float* __restrict__ Wc, u16* __restrict__ At2) {
    int idx = blockIdx.x * 256 + threadIdx.x;          // < 1179648
    int s = idx & 7;
    int lane = (idx >> 3) & 63;
    int mb = (idx >> 9) & 3;
    int mi = (idx >> 11) & 1;
    int ck = (idx >> 12) & 1;
    int rem = idx >> 13;                                // 0..143
    int r = rem % 9;
    int rem2 = rem / 9;                                 // 0..15
    int hf = rem2 & 1;
    int e = rem2 >> 1;
    int l15 = lane & 15, quad = lane >> 4;
    int o = mi * 64 + mb * 16 + l15;
    int cin = hf * 64 + ck * 32 + quad * 8 + s;
    size_t src = (((size_t)e * 128 + o) * 128 + cin) * 9 + r;
    At2[idx] = f2bf(Wc[src]);
}

// ---------------------------------------------------------------- pre: Wp -> bf16
__global__ void pre_wp(const float* __restrict__ Wp, u16* __restrict__ Wpt) {
    int i = blockIdx.x * 256 + threadIdx.x;
    if (i < 131072) Wpt[i] = f2bf(Wp[i]);
}

// ---------------------------------------------------------------- fused dual-expert gate block
// Block: (hs, b, g) -> 2 output rows, both top-2 experts, writes out[g] once (no atomics).
// 512 threads = 8 waves: mi = M-half (64 ch), ni = quarter of 192 px (48 px, j=3 tiles).
// Conv: 36 steps x 2 sub-phases (m201 read-ahead discipline):
//   SubA(g): STAGE(g+2) DMA; ds_read af1(g);            MFMA expert0(g); barrier
//   SubB(g): ds_read bv(g+1)+af0(g+1);                  MFMA expert1(g); vmcnt(0); barrier
// Every MFMA cluster consumes fragments read ONE SUB-PHASE EARLIER (in flight across the
// barrier -> LDS pipe overlaps matrix pipe). Cross-barrier reg carry <= 28 VGPR (no R4 ring).
__launch_bounds__(512, 2)
__global__ void expert_kernel(const u16* __restrict__ Xt, const u16* __restrict__ At2,
                              const u16* __restrict__ Wpt,
                              const float* __restrict__ bc, const float* __restrict__ bp,
                              const float* __restrict__ ws, float* __restrict__ out) {
    int hs = blockIdx.x, b = blockIdx.y, g = blockIdx.z;
    int h0 = hs * 2;
    int t = threadIdx.x, lane = t & 63, wv = t >> 6;
    int mi = wv & 1, ni = wv >> 1;                 // ni 0..3
    int l15 = lane & 15, quad = lane >> 4, q8 = quad * 8;
    int nrow = ni >> 1;                            // local output row 0/1
    int ncb = (ni & 1) * 48;                       // pixel-col base

    const int* iw = (const int*)(ws + 1344);
    const float* wt = ws + 1408;
    int ee[2];
    float wwt[2];
    ee[0] = iw[g * 16 + b * 2 + 0]; ee[1] = iw[g * 16 + b * 2 + 1];
    wwt[0] = wt[g * 16 + b * 2 + 0]; wwt[1] = wt[g * 16 + b * 2 + 1];

    // LDS: halo Hs[4][98][64] bf16 @0 (50176 B) | A-ring @50176: 3 x 16384 B = 99328 total
    //      epilogue overlays @0: part_s[192][12] f32 (9216) + v_s[192][128] bf16 (49152)
    __shared__ __align__(16) char smem[99328];
    u16* Hs = (u16*)smem;                          // halo row stride 6272 u16 = 12544 B
    float* part_s = (float*)smem;
    u16* v_s = (u16*)(smem + 9216);

    f32x4 zero = {0.f, 0.f, 0.f, 0.f};
    f32x4 acc[2][12];                              // [expert][mb*3 + j]
    #pragma unroll
    for (int i = 0; i < 12; ++i) { acc[0][i] = zero; acc[1][i] = zero; }

    int abase = mi * 2048 + lane * 8;              // u16 offset within a ring slot (per expert)

    const u16* Ab0 = At2 + (size_t)(ee[0] * 2) * 73728;   // expert bases (hf=0)
    const u16* Ab1 = At2 + (size_t)(ee[1] * 2) * 73728;

    #define ASRC(P, U) ((P) + ((U) >= 18 ? 73728 + ((U) - 18) * 4096 : (U) * 4096))
    #define STAGE(U) { u16* ab_ = (u16*)(smem + 50176 + ((U) % 3) * 16384);          \
                       gload_lds16(ASRC(Ab0, (U)) + t * 8, ab_ + t * 8);             \
                       gload_lds16(ASRC(Ab1, (U)) + t * 8, ab_ + 4096 + t * 8); }
    // read a 4-frag A set from ring slot G%3 (+XOFF = 0 for expert0 half, 4096 for expert1)
    #define RD_AF(DST, G, XOFF) { const u16* abr_ = (const u16*)(smem + 50176 + ((G) % 3) * 16384) + (XOFF); \
        _Pragma("unroll") for (int mb_ = 0; mb_ < 4; ++mb_) DST[mb_] = *(const short8*)(abr_ + abase + mb_ * 512); }
    // read the 3 B-frags for conv step G (halo layout fixed per hf)
    #define RD_BV(DST, G) { const int s_ = (G) % 18, r_ = s_ >> 1, ck_ = s_ & 1;     \
        const int dyi_ = r_ / 3, dxi_ = r_ - dyi_ * 3, hb_ = (nrow + dyi_) * 12544;  \
        _Pragma("unroll") for (int j_ = 0; j_ < 3; ++j_) {                           \
            int col_ = ncb + j_ * 16 + l15 + dxi_;                                   \
            int ba_ = hb_ + col_ * 128 + ((q8 ^ (((col_ - 1) & 7) << 3)) << 1);      \
            DST[j_] = *(const short8*)(smem + (ba_ ^ (ck_ << 6))); } }
    #define MFMA12(XP, AF, BV) { _Pragma("unroll") for (int mb_ = 0; mb_ < 4; ++mb_) \
        _Pragma("unroll") for (int j_ = 0; j_ < 3; ++j_)                             \
            acc[XP][mb_ * 3 + j_] = __builtin_amdgcn_mfma_f32_16x16x32_bf16(AF[mb_], BV[j_], acc[XP][mb_ * 3 + j_], 0, 0, 0); }

    // ======== prologue: zero borders/OOB rows, stage hf0 halo, stage slots 0,1 ========
    {
        uint4 z; z.x = z.y = z.z = z.w = 0u;
        #pragma unroll
        for (int rr = 0; rr < 4; ++rr) {
            int row = h0 - 1 + rr;
            if (row < 0 || row >= 96)              // OOB rows: zero once, valid for both hf
                for (int i = t; i < 784; i += 512) *(uint4*)(Hs + rr * 6272 + i * 8) = z;
        }
        if (t < 64) {                              // border cols 0 / 97 (persist across hf)
            int rr = t >> 4, cs = (t >> 3) & 1, p = t & 7;
            *(uint4*)(Hs + rr * 6272 + cs * 97 * 64 + p * 8) = z;
        }
        const u16* Xb = Xt + (size_t)(b * 2 + 0) * 96 * 6144;
        #pragma unroll
        for (int rr = 0; rr < 4; ++rr) {
            int row = h0 - 1 + rr;
            if (row >= 0 && row < 96) {
                const u16* src = Xb + (size_t)row * 6144;
                u16* dst = Hs + rr * 6272 + 64;
                for (int i = t; i < 768; i += 512) gload_lds16(src + i * 8, dst + i * 8);
            }
        }
    }
    STAGE(0); STAGE(1);
    __syncthreads();                               // full drain once (vm + lgkm + barrier)

    // ======== conv: 36 steps, 2 sub-phases each ========
    short8 af0[4], af1[4], bvA[3], bvB[3];

    #pragma unroll
    for (int hf = 0; hf < 2; ++hf) {
        if (hf == 1) {
            // hf boundary flush: all old-halo ds_reads drained (lgkmcnt(0) at end of half 0)
            const u16* Xb = Xt + (size_t)(b * 2 + 1) * 96 * 6144;
            #pragma unroll
            for (int rr = 0; rr < 4; ++rr) {
                int row = h0 - 1 + rr;
                if (row >= 0 && row < 96) {
                    const u16* src = Xb + (size_t)row * 6144;
                    u16* dst = Hs + rr * 6272 + 64;
                    for (int i = t; i < 768; i += 512) gload_lds16(src + i * 8, dst + i * 8);
                }
            }
            asm volatile("s_waitcnt vmcnt(0)" ::: "memory");
            __builtin_amdgcn_s_barrier();
        }
        // per-half pipeline prime: read step g0's af0 + bv (consumed in SubA(u=0))
        RD_AF(af0, hf * 18, 0);
        RD_BV(bvA, hf * 18);

        #pragma unroll
        for (int u = 0; u < 18; ++u) {
            const int gg = hf * 18 + u;
            // ---- SubA(gg): STAGE(gg+2) || read af1(gg) || MFMA expert0(gg) ----
            if (gg + 2 <= 35) STAGE(gg + 2);
            RD_AF(af1, gg, 4096);
            __builtin_amdgcn_s_setprio(1);
            if (u & 1) { MFMA12(0, af0, bvB); } else { MFMA12(0, af0, bvA); }
            __builtin_amdgcn_s_setprio(0);
            __builtin_amdgcn_s_barrier();
            // ---- SubB(gg): read bv(gg+1)+af0(gg+1) || MFMA expert1(gg) ----
            if (u < 17) {
                if (u & 1) { RD_BV(bvA, gg + 1); } else { RD_BV(bvB, gg + 1); }
                RD_AF(af0, gg + 1, 0);
            }
            __builtin_amdgcn_s_setprio(1);
            if (u & 1) { MFMA12(1, af1, bvB); } else { MFMA12(1, af1, bvA); }
            __builtin_amdgcn_s_setprio(0);
            asm volatile("s_waitcnt vmcnt(0)" ::: "memory");
            if (u == 17) asm volatile("s_waitcnt lgkmcnt(0)" ::: "memory");
            __builtin_amdgcn_s_barrier();
        }
    }
    #undef STAGE
    #undef ASRC
    #undef RD_AF
    #undef RD_BV
    #undef MFMA12

    // ======== epilogue per expert: bias+relu+squash -> v_s -> pointwise ========
    #pragma unroll
    for (int xp = 0; xp < 2; ++xp) {
        int e_ = ee[xp];
        __syncthreads();   // xp=0: conv LDS reads done; xp=1: pw0's v_s reads done
        #pragma unroll
        for (int j = 0; j < 3; ++j) {
            int n = ni * 48 + j * 16 + l15;
            float ssum = 0.f;
            #pragma unroll
            for (int mb = 0; mb < 4; ++mb) {
                f32x4 a = acc[xp][mb * 3 + j];
                #pragma unroll
                for (int rg = 0; rg < 4; ++rg) {
                    float u = fmaxf(a[rg] + bc[e_ * 128 + mi * 64 + mb * 16 + quad * 4 + rg], 0.f);
                    a[rg] = u; ssum += u * u;
                }
                acc[xp][mb * 3 + j] = a;
            }
            part_s[n * 12 + mi * 4 + quad] = ssum;
        }
        __syncthreads();
        #pragma unroll
        for (int j = 0; j < 3; ++j) {
            int n = ni * 48 + j * 16 + l15;
            f32x4 p0 = *(const f32x4*)(part_s + n * 12);
            f32x4 p1 = *(const f32x4*)(part_s + n * 12 + 4);
            float sn2 = p0[0] + p0[1] + p0[2] + p0[3] + p1[0] + p1[1] + p1[2] + p1[3];
            float fsj = sn2 / ((1.f + sn2) * sqrtf(sn2 + 1e-8f));
            int sw = (n & 7) << 3;
            #pragma unroll
            for (int mb = 0; mb < 4; ++mb) {
                f32x4 a = acc[xp][mb * 3 + j];
                short4 pk;
                pk.x = (short)f2bf(a[0] * fsj); pk.y = (short)f2bf(a[1] * fsj);
                pk.z = (short)f2bf(a[2] * fsj); pk.w = (short)f2bf(a[3] * fsj);
                int cb = mb * 16 + quad * 4;
                *(short4*)(v_s + n * 128 + ((cb ^ sw) | (mi << 6))) = pk;
            }
        }
        __syncthreads();
        #pragma unroll
        for (int i = 0; i < 12; ++i) acc[xp][i] = zero;
        const u16* We_ = Wpt + (size_t)e_ * 16384;
        #pragma unroll
        for (int kk = 0; kk < 4; ++kk) {
            short8 af[4];
            #pragma unroll
            for (int mb = 0; mb < 4; ++mb)
                af[mb] = *(const short8*)(We_ + (mi * 64 + mb * 16 + l15) * 128 + kk * 32 + q8);
            short8 bvv[3];
            #pragma unroll
            for (int j = 0; j < 3; ++j) {
                int n = ni * 48 + j * 16 + l15;
                int sw = (n & 7) << 3;
                int pos = ((kk & 2) << 5) | ((((kk & 1) << 5) + q8) ^ sw);
                bvv[j] = *(const short8*)(v_s + n * 128 + pos);
            }
            #pragma unroll
            for (int mb = 0; mb < 4; ++mb)
                #pragma unroll
                for (int j = 0; j < 3; ++j)
                    acc[xp][mb * 3 + j] = __builtin_amdgcn_mfma_f32_16x16x32_bf16(af[mb], bvv[j], acc[xp][mb * 3 + j], 0, 0, 0);
        }
    }

    // ======== mix + store (exactly once, coalesced) ========
    int row = h0 + nrow;
    #pragma unroll
    for (int mb = 0; mb < 4; ++mb)
        #pragma unroll
        for (int rg = 0; rg < 4; ++rg) {
            int o = mi * 64 + mb * 16 + quad * 4 + rg;
            float y0b = bp[ee[0] * 128 + o];
            float y1b = bp[ee[1] * 128 + o];
            size_t obase = (size_t)g * OPG + ((size_t)(b * 128 + o)) * CHW + (size_t)row * 96;
            #pragma unroll
            for (int j = 0; j < 3; ++j) {
                float y0 = acc[0][mb * 3 + j][rg] + y0b;
                float y1 = acc[1][mb * 3 + j][rg] + y1b;
                out[obase + ncb + j * 16 + l15] = wwt[0] * y0 + wwt[1] * y1;
            }
        }
}

// ---------------------------------------------------------------- launch
extern "C" void kernel_launch(void* const* d_in, const int* in_sizes, int n_in,
                              void* d_out, int out_size, void* d_ws, size_t ws_size,
                              hipStream_t stream) {
    const float* x  = (const float*)d_in[0];
    const float* G  = (const float*)d_in[1];
    const float* Wc = (const float*)d_in[2];
    const float* bc = (const float*)d_in[3];
    const float* Wp = (const float*)d_in[4];
    const float* bp = (const float*)d_in[5];
    float* out = (float*)d_out;
    float* ws  = (float*)d_ws;
    u16* Xt  = (u16*)((char*)d_ws + WS_XT);
    u16* At2 = (u16*)((char*)d_ws + WS_AT);
    u16* Wpt = (u16*)((char*)d_ws + WS_WPT);

    gap_kernel<<<dim3(1024), dim3(256), 0, stream>>>(x, ws);
    gate_kernel<<<dim3(1), dim3(64), 0, stream>>>(G, ws, out + (size_t)4 * OPG);
    pre_x<<<dim3(96, 8), dim3(256), 0, stream>>>(x, Xt);
    pre_wc2<<<dim3(4608), dim3(256), 0, stream>>>(Wc, At2);
    pre_wp<<<dim3(512), dim3(256), 0, stream>>>(Wp, Wpt);
    expert_kernel<<<dim3(48, 8, 4), dim3(512), 0, stream>>>(Xt, At2, Wpt, bc, bp, ws, out);
}

// Round 6
// 423.322 us; speedup vs baseline: 1.0642x; 1.0162x over previous
//
#include <hip/hip_runtime.h>
#include <math.h>

// E=8, TOP=2, C=128, H=96, W=96, B=8, NUM_GATES=4, KH=3
#define CHW 9216
#define OPG 9437184  // 8*128*96*96

typedef unsigned short u16;
typedef __attribute__((ext_vector_type(8))) short short8;   // 8 x bf16 (4 VGPR)
typedef __attribute__((ext_vector_type(4))) float f32x4;

// ws layout (bytes):
// [0, 8192)            gating (floats): x_gap[1024]; idx2[4][8][2] int @1344f; wt2[4][8][2] @1408f
// [8192, 18882560)     X_t  bf16 [b][hf][h][w][c64]  (c swizzled: c^((w&7)<<3))
// [18882560, 21241856) A_t2 bf16 [e][hf][r][ck][mi][mb][lane][8]  (wave-fragment order)
// [21241856, 21504000) Wp_t bf16 [e][o][c128]
#define WS_XT  8192
#define WS_AT  18882560
#define WS_WPT 21241856

__device__ __forceinline__ u16 f2bf(float f) {
    unsigned u = __float_as_uint(f);
    u += 0x7fff + ((u >> 16) & 1);      // RNE
    return (u16)(u >> 16);
}

// async global->LDS, 16B per lane; LDS dest must be wave-uniform base + lane*16
__device__ __forceinline__ void gload_lds16(const void* g, void* l) {
    __builtin_amdgcn_global_load_lds(
        (const __attribute__((address_space(1))) void*)g,
        (__attribute__((address_space(3))) void*)l, 16, 0, 0);
}

// ---------------------------------------------------------------- x_gap
__global__ void gap_kernel(const float* __restrict__ x, float* __restrict__ xgap) {
    int bc = blockIdx.x;
    const float* p = x + (size_t)bc * CHW;
    float s = 0.f;
    for (int i = threadIdx.x; i < CHW; i += 256) s += p[i];
    __shared__ float red[256];
    red[threadIdx.x] = s;
    __syncthreads();
    for (int off = 128; off > 0; off >>= 1) {
        if (threadIdx.x < off) red[threadIdx.x] += red[threadIdx.x + off];
        __syncthreads();
    }
    if (threadIdx.x == 0) xgap[bc] = red[0] * (1.0f / 9216.0f);
}

// ---------------------------------------------------------------- gating (exact fp32)
__global__ void gate_kernel(const float* __restrict__ G, float* __restrict__ ws,
                            float* __restrict__ loss_out) {
    __shared__ float gap_s[1024];
    __shared__ float logits[64];
    __shared__ float probs[64];
    __shared__ float vsum[8];
    __shared__ float losses[4];
    int t = threadIdx.x;
    for (int i = t; i < 1024; i += 64) gap_s[i] = ws[i];
    int b = t >> 3, e = t & 7;
    int* iw = (int*)(ws + 1344);
    float* wt = ws + 1408;
    __syncthreads();
    for (int g = 0; g < 4; ++g) {
        float acc = 0.f;
        const float* Gg = G + g * 1024;
        for (int c = 0; c < 128; ++c) acc += gap_s[b * 128 + c] * Gg[c * 8 + e];
        logits[t] = acc;
        __syncthreads();
        float m = -1e30f;
        for (int j = 0; j < 8; ++j) m = fmaxf(m, logits[b * 8 + j]);
        float den = 0.f;
        for (int j = 0; j < 8; ++j) den += expf(logits[b * 8 + j] - m);
        float pr = expf(acc - m) / den;
        probs[t] = pr;
        __syncthreads();
        if (e == 0) {
            int i0 = 0; float v0 = probs[b * 8];
            for (int j = 1; j < 8; ++j) { float v = probs[b * 8 + j]; if (v > v0) { v0 = v; i0 = j; } }
            int i1 = -1; float v1 = -1e30f;
            for (int j = 0; j < 8; ++j) { if (j == i0) continue; float v = probs[b * 8 + j]; if (v > v1) { v1 = v; i1 = j; } }
            float r = expf(v1 - v0);              // softmax over [v0,v1]
            float inv = 1.f / (1.f + r);
            iw[g * 16 + b * 2 + 0] = i0;
            iw[g * 16 + b * 2 + 1] = i1;
            wt[g * 16 + b * 2 + 0] = inv;
            wt[g * 16 + b * 2 + 1] = r * inv;
        }
        if (t < 8) {
            float v = 0.f;
            for (int bb = 0; bb < 8; ++bb) v += probs[bb * 8 + t];
            vsum[t] = v;
        }
        __syncthreads();
        if (t == 0) {
            float mean = 0.f;
            for (int j = 0; j < 8; ++j) mean += vsum[j];
            mean *= 0.125f;
            float var = 0.f;
            for (int j = 0; j < 8; ++j) { float d = vsum[j] - mean; var += d * d; }
            var *= (1.f / 7.f);
            losses[g] = var / (mean * mean + 1e-10f);
        }
        __syncthreads();
    }
    if (t == 0) loss_out[0] = 0.25f * (losses[0] + losses[1] + losses[2] + losses[3]);
}

// ---------------------------------------------------------------- pre: x -> bf16 swizzled
__global__ void pre_x(const float* __restrict__ x, u16* __restrict__ Xt) {
    int h = blockIdx.x, b = blockIdx.y, t = threadIdx.x;
    __shared__ u16 lds[12288];
    const float* xb = x + ((size_t)b * 128) * CHW + h * 96;
    for (int i = t; i < 12288; i += 256) {
        int c = i / 96, w = i - c * 96;
        lds[(c >> 6) * 6144 + w * 64 + ((c & 63) ^ ((w & 7) << 3))] = f2bf(xb[(size_t)c * CHW + w]);
    }
    __syncthreads();
    const unsigned* l32 = (const unsigned*)lds;
    unsigned* o32 = (unsigned*)Xt;
    for (int i = t; i < 6144; i += 256) {
        int hf = (i >= 3072) ? 1 : 0;
        int rem = i - hf * 3072;
        o32[((size_t)(b * 2 + hf) * 96 + h) * 3072 + rem] = l32[i];
    }
}

// ---------------------------------------------------------------- pre: Wc -> A_t2 (fragment order)
// At2 u16 index: (((((e*2+hf)*9+r)*2+ck)*2+mi)*4+mb)*512 + lane*8 + s
// value = Wc[e][o=mi*64+mb*16+(lane&15)][cin=hf*64+ck*32+(lane>>4)*8+s][tap r]
__global__ void pre_wc2(const float* __restrict__ Wc, u16* __restrict__ At2) {
    int idx = blockIdx.x * 256 + threadIdx.x;          // < 1179648
    int s = idx & 7;
    int lane = (idx >> 3) & 63;
    int mb = (idx >> 9) & 3;
    int mi = (idx >> 11) & 1;
    int ck = (idx >> 12) & 1;
    int rem = idx >> 13;                                // 0..143
    int r = rem % 9;
    int rem2 = rem / 9;                                 // 0..15
    int hf = rem2 & 1;
    int e = rem2 >> 1;
    int l15 = lane & 15, quad = lane >> 4;
    int o = mi * 64 + mb * 16 + l15;
    int cin = hf * 64 + ck * 32 + quad * 8 + s;
    size_t src = (((size_t)e * 128 + o) * 128 + cin) * 9 + r;
    At2[idx] = f2bf(Wc[src]);
}

// ---------------------------------------------------------------- pre: Wp -> bf16
__global__ void pre_wp(const float* __restrict__ Wp, u16* __restrict__ Wpt) {
    int i = blockIdx.x * 256 + threadIdx.x;
    if (i < 131072) Wpt[i] = f2bf(Wp[i]);
}

// ---------------------------------------------------------------- fused dual-expert gate block
// Block: (hs, b, g) -> 2 output rows, both top-2 experts, writes out[g] once (no atomics).
// 512 threads = 8 waves: mi = M-half (64 ch), ni = quarter of 192 px (48 px, j=3 tiles).
// Conv: 36 steps, ONE runtime barrier per step; intra-step ordering pinned by
// sched_barrier(0) (compile-time, no convoy). Per step:
//   STAGE(u+2); read af1(u)            | sched_barrier
//   MFMA e0 x12 (af0(u), bv(u))        | sched_barrier   <- operands read LAST phase
//   read bv(u+1), af0(u+1)             | sched_barrier   <- fly across the barrier
//   MFMA e1 x12 (af1(u), bv(u))        | vmcnt(0); s_barrier
// Every MFMA cluster consumes fragments issued >=1 cluster earlier (~460cy MFMA cover
// vs ~120-250cy LDS latency). Frag regs: af0+af1+bvA+bvB = 56 VGPR (R5 level, no spill).
__launch_bounds__(512, 2)
__global__ void expert_kernel(const u16* __restrict__ Xt, const u16* __restrict__ At2,
                              const u16* __restrict__ Wpt,
                              const float* __restrict__ bc, const float* __restrict__ bp,
                              const float* __restrict__ ws, float* __restrict__ out) {
    int hs = blockIdx.x, b = blockIdx.y, g = blockIdx.z;
    int h0 = hs * 2;
    int t = threadIdx.x, lane = t & 63, wv = t >> 6;
    int mi = wv & 1, ni = wv >> 1;                 // ni 0..3
    int l15 = lane & 15, quad = lane >> 4, q8 = quad * 8;
    int nrow = ni >> 1;                            // local output row 0/1
    int ncb = (ni & 1) * 48;                       // pixel-col base

    const int* iw = (const int*)(ws + 1344);
    const float* wt = ws + 1408;
    int ee[2];
    float wwt[2];
    ee[0] = iw[g * 16 + b * 2 + 0]; ee[1] = iw[g * 16 + b * 2 + 1];
    wwt[0] = wt[g * 16 + b * 2 + 0]; wwt[1] = wt[g * 16 + b * 2 + 1];

    // LDS: halo Hs[4][98][64] bf16 @0 (50176 B) | A-ring @50176: 3 x 16384 B = 99328 total
    //      epilogue overlays @0: part_s[192][12] f32 (9216) + v_s[192][128] bf16 (49152)
    __shared__ __align__(16) char smem[99328];
    u16* Hs = (u16*)smem;                          // halo row stride 6272 u16 = 12544 B
    float* part_s = (float*)smem;
    u16* v_s = (u16*)(smem + 9216);

    f32x4 zero = {0.f, 0.f, 0.f, 0.f};
    f32x4 acc[2][12];                              // [expert][mb*3 + j]
    #pragma unroll
    for (int i = 0; i < 12; ++i) { acc[0][i] = zero; acc[1][i] = zero; }

    int abase = mi * 2048 + lane * 8;              // u16 offset within a ring slot (per expert)

    const u16* Ab0 = At2 + (size_t)(ee[0] * 2) * 73728;   // expert bases (hf=0)
    const u16* Ab1 = At2 + (size_t)(ee[1] * 2) * 73728;

    #define ASRC(P, U) ((P) + ((U) >= 18 ? 73728 + ((U) - 18) * 4096 : (U) * 4096))
    #define STAGE(U) { u16* ab_ = (u16*)(smem + 50176 + ((U) % 3) * 16384);          \
                       gload_lds16(ASRC(Ab0, (U)) + t * 8, ab_ + t * 8);             \
                       gload_lds16(ASRC(Ab1, (U)) + t * 8, ab_ + 4096 + t * 8); }
    // read a 4-frag A set from ring slot G%3 (+XOFF = 0 for expert0 half, 4096 for expert1)
    #define RD_AF(DST, G, XOFF) { const u16* abr_ = (const u16*)(smem + 50176 + ((G) % 3) * 16384) + (XOFF); \
        _Pragma("unroll") for (int mb_ = 0; mb_ < 4; ++mb_) DST[mb_] = *(const short8*)(abr_ + abase + mb_ * 512); }
    // read the 3 B-frags for conv step G (halo layout fixed per hf)
    #define RD_BV(DST, G) { const int s_ = (G) % 18, r_ = s_ >> 1, ck_ = s_ & 1;     \
        const int dyi_ = r_ / 3, dxi_ = r_ - dyi_ * 3, hb_ = (nrow + dyi_) * 12544;  \
        _Pragma("unroll") for (int j_ = 0; j_ < 3; ++j_) {                           \
            int col_ = ncb + j_ * 16 + l15 + dxi_;                                   \
            int ba_ = hb_ + col_ * 128 + ((q8 ^ (((col_ - 1) & 7) << 3)) << 1);      \
            DST[j_] = *(const short8*)(smem + (ba_ ^ (ck_ << 6))); } }
    #define MFMA12(XP, AF, BV) { _Pragma("unroll") for (int mb_ = 0; mb_ < 4; ++mb_) \
        _Pragma("unroll") for (int j_ = 0; j_ < 3; ++j_)                             \
            acc[XP][mb_ * 3 + j_] = __builtin_amdgcn_mfma_f32_16x16x32_bf16(AF[mb_], BV[j_], acc[XP][mb_ * 3 + j_], 0, 0, 0); }
    #define SBAR() __builtin_amdgcn_sched_barrier(0)

    // ======== prologue: zero borders/OOB rows, stage hf0 halo, stage slots 0,1 ========
    {
        uint4 z; z.x = z.y = z.z = z.w = 0u;
        #pragma unroll
        for (int rr = 0; rr < 4; ++rr) {
            int row = h0 - 1 + rr;
            if (row < 0 || row >= 96)              // OOB rows: zero once, valid for both hf
                for (int i = t; i < 784; i += 512) *(uint4*)(Hs + rr * 6272 + i * 8) = z;
        }
        if (t < 64) {                              // border cols 0 / 97 (persist across hf)
            int rr = t >> 4, cs = (t >> 3) & 1, p = t & 7;
            *(uint4*)(Hs + rr * 6272 + cs * 97 * 64 + p * 8) = z;
        }
        const u16* Xb = Xt + (size_t)(b * 2 + 0) * 96 * 6144;
        #pragma unroll
        for (int rr = 0; rr < 4; ++rr) {
            int row = h0 - 1 + rr;
            if (row >= 0 && row < 96) {
                const u16* src = Xb + (size_t)row * 6144;
                u16* dst = Hs + rr * 6272 + 64;
                for (int i = t; i < 768; i += 512) gload_lds16(src + i * 8, dst + i * 8);
            }
        }
    }
    STAGE(0); STAGE(1);
    __syncthreads();                               // full drain once (vm + lgkm + barrier)

    // ======== conv: 36 steps, 1 barrier each, sched_barrier-pinned overlap ========
    short8 af0[4], af1[4], bvA[3], bvB[3];

    #pragma unroll
    for (int hf = 0; hf < 2; ++hf) {
        if (hf == 1) {
            // hf boundary flush: all old-halo ds_reads consumed by step-17's MFMAs
            const u16* Xb = Xt + (size_t)(b * 2 + 1) * 96 * 6144;
            #pragma unroll
            for (int rr = 0; rr < 4; ++rr) {
                int row = h0 - 1 + rr;
                if (row >= 0 && row < 96) {
                    const u16* src = Xb + (size_t)row * 6144;
                    u16* dst = Hs + rr * 6272 + 64;
                    for (int i = t; i < 768; i += 512) gload_lds16(src + i * 8, dst + i * 8);
                }
            }
            asm volatile("s_waitcnt vmcnt(0)" ::: "memory");
            __builtin_amdgcn_s_barrier();
        }
        // per-half pipeline prime: read step g0's af0 + bv (consumed by first MFMA0)
        RD_AF(af0, hf * 18, 0);
        RD_BV(bvA, hf * 18);

        #pragma unroll
        for (int u = 0; u < 18; ++u) {
            const int gg = hf * 18 + u;
            // ---- region 1: next-slot DMA + af1(gg) reads ----
            if (gg + 2 <= 35) STAGE(gg + 2);
            RD_AF(af1, gg, 4096);
            SBAR();
            // ---- region 2: MFMA expert0(gg) — operands read last phase ----
            __builtin_amdgcn_s_setprio(1);
            if (u & 1) { MFMA12(0, af0, bvB); } else { MFMA12(0, af0, bvA); }
            __builtin_amdgcn_s_setprio(0);
            SBAR();
            // ---- region 3: reads for step gg+1 (fly across the barrier) ----
            if (u < 17) {
                if (u & 1) { RD_BV(bvA, gg + 1); } else { RD_BV(bvB, gg + 1); }
                RD_AF(af0, gg + 1, 0);
            }
            SBAR();
            // ---- region 4: MFMA expert1(gg) — af1 latency hidden under MFMA0 ----
            __builtin_amdgcn_s_setprio(1);
            if (u & 1) { MFMA12(1, af1, bvB); } else { MFMA12(1, af1, bvA); }
            __builtin_amdgcn_s_setprio(0);
            asm volatile("s_waitcnt vmcnt(0)" ::: "memory");
            if (u == 17) asm volatile("s_waitcnt lgkmcnt(0)" ::: "memory");
            __builtin_amdgcn_s_barrier();
        }
    }
    #undef STAGE
    #undef ASRC
    #undef RD_AF
    #undef RD_BV
    #undef MFMA12
    #undef SBAR

    // ======== epilogue per expert: bias+relu+squash -> v_s -> pointwise ========
    #pragma unroll
    for (int xp = 0; xp < 2; ++xp) {
        int e_ = ee[xp];
        __syncthreads();   // xp=0: conv LDS reads done; xp=1: pw0's v_s reads done
        #pragma unroll
        for (int j = 0; j < 3; ++j) {
            int n = ni * 48 + j * 16 + l15;
            float ssum = 0.f;
            #pragma unroll
            for (int mb = 0; mb < 4; ++mb) {
                f32x4 a = acc[xp][mb * 3 + j];
                #pragma unroll
                for (int rg = 0; rg < 4; ++rg) {
                    float u = fmaxf(a[rg] + bc[e_ * 128 + mi * 64 + mb * 16 + quad * 4 + rg], 0.f);
                    a[rg] = u; ssum += u * u;
                }
                acc[xp][mb * 3 + j] = a;
            }
            part_s[n * 12 + mi * 4 + quad] = ssum;
        }
        __syncthreads();
        #pragma unroll
        for (int j = 0; j < 3; ++j) {
            int n = ni * 48 + j * 16 + l15;
            f32x4 p0 = *(const f32x4*)(part_s + n * 12);
            f32x4 p1 = *(const f32x4*)(part_s + n * 12 + 4);
            float sn2 = p0[0] + p0[1] + p0[2] + p0[3] + p1[0] + p1[1] + p1[2] + p1[3];
            float fsj = sn2 / ((1.f + sn2) * sqrtf(sn2 + 1e-8f));
            int sw = (n & 7) << 3;
            #pragma unroll
            for (int mb = 0; mb < 4; ++mb) {
                f32x4 a = acc[xp][mb * 3 + j];
                short4 pk;
                pk.x = (short)f2bf(a[0] * fsj); pk.y = (short)f2bf(a[1] * fsj);
                pk.z = (short)f2bf(a[2] * fsj); pk.w = (short)f2bf(a[3] * fsj);
                int cb = mb * 16 + quad * 4;
                *(short4*)(v_s + n * 128 + ((cb ^ sw) | (mi << 6))) = pk;
            }
        }
        __syncthreads();
        #pragma unroll
        for (int i = 0; i < 12; ++i) acc[xp][i] = zero;
        const u16* We_ = Wpt + (size_t)e_ * 16384;
        #pragma unroll
        for (int kk = 0; kk < 4; ++kk) {
            short8 af[4];
            #pragma unroll
            for (int mb = 0; mb < 4; ++mb)
                af[mb] = *(const short8*)(We_ + (mi * 64 + mb * 16 + l15) * 128 + kk * 32 + q8);
            short8 bvv[3];
            #pragma unroll
            for (int j = 0; j < 3; ++j) {
                int n = ni * 48 + j * 16 + l15;
                int sw = (n & 7) << 3;
                int pos = ((kk & 2) << 5) | ((((kk & 1) << 5) + q8) ^ sw);
                bvv[j] = *(const short8*)(v_s + n * 128 + pos);
            }
            #pragma unroll
            for (int mb = 0; mb < 4; ++mb)
                #pragma unroll
                for (int j = 0; j < 3; ++j)
                    acc[xp][mb * 3 + j] = __builtin_amdgcn_mfma_f32_16x16x32_bf16(af[mb], bvv[j], acc[xp][mb * 3 + j], 0, 0, 0);
        }
    }

    // ======== mix + store (exactly once, coalesced) ========
    int row = h0 + nrow;
    #pragma unroll
    for (int mb = 0; mb < 4; ++mb)
        #pragma unroll
        for (int rg = 0; rg < 4; ++rg) {
            int o = mi * 64 + mb * 16 + quad * 4 + rg;
            float y0b = bp[ee[0] * 128 + o];
            float y1b = bp[ee[1] * 128 + o];
            size_t obase = (size_t)g * OPG + ((size_t)(b * 128 + o)) * CHW + (size_t)row * 96;
            #pragma unroll
            for (int j = 0; j < 3; ++j) {
                float y0 = acc[0][mb * 3 + j][rg] + y0b;
                float y1 = acc[1][mb * 3 + j][rg] + y1b;
                out[obase + ncb + j * 16 + l15] = wwt[0] * y0 + wwt[1] * y1;
            }
        }
}

// ---------------------------------------------------------------- launch
extern "C" void kernel_launch(void* const* d_in, const int* in_sizes, int n_in,
                              void* d_out, int out_size, void* d_ws, size_t ws_size,
                              hipStream_t stream) {
    const float* x  = (const float*)d_in[0];
    const float* G  = (const float*)d_in[1];
    const float* Wc = (const float*)d_in[2];
    const float* bc = (const float*)d_in[3];
    const float* Wp = (const float*)d_in[4];
    const float* bp = (const float*)d_in[5];
    float* out = (float*)d_out;
    float* ws  = (float*)d_ws;
    u16* Xt  = (u16*)((char*)d_ws + WS_XT);
    u16* At2 = (u16*)((char*)d_ws + WS_AT);
    u16* Wpt = (u16*)((char*)d_ws + WS_WPT);

    gap_kernel<<<dim3(1024), dim3(256), 0, stream>>>(x, ws);
    gate_kernel<<<dim3(1), dim3(64), 0, stream>>>(G, ws, out + (size_t)4 * OPG);
    pre_x<<<dim3(96, 8), dim3(256), 0, stream>>>(x, Xt);
    pre_wc2<<<dim3(4608), dim3(256), 0, stream>>>(Wc, At2);
    pre_wp<<<dim3(512), dim3(256), 0, stream>>>(Wp, Wpt);
    expert_kernel<<<dim3(48, 8, 4), dim3(512), 0, stream>>>(Xt, At2, Wpt, bc, bp, ws, out);
}